// Round 1
// baseline (3292.407 us; speedup 1.0000x reference)
//
#include <hip/hip_runtime.h>
#include <cstdint>
#include <cstddef>

typedef unsigned short u16;
typedef __attribute__((ext_vector_type(8))) __bf16 bf16x8;
typedef __attribute__((ext_vector_type(4))) float f32x4;

#define DD 1024            // D
#define MM 16384           // B*T rows
#define NCH 64             // scan chunks
#define CLEN 64            // chunk length (NCH*CLEN = T = 4096)
#define EPAD 136           // epilogue LDS row stride (128-col tiles), u16
#define EPAD2 264          // epilogue LDS row stride (256-col tiles), u16

__device__ __forceinline__ u16 f2b(float f) {
    uint32_t u = __float_as_uint(f);
    u += 0x7fffu + ((u >> 16) & 1u);       // round-to-nearest-even
    return (u16)(u >> 16);
}
__device__ __forceinline__ float b2f(u16 v) {
    return __uint_as_float(((uint32_t)v) << 16);
}
__device__ __forceinline__ float sigmoid_f(float v) { return 1.f / (1.f + __expf(-v)); }
__device__ __forceinline__ float gelu_f(float v) {
    return 0.5f * v * (1.f + erff(v * 0.70710678118654752f));
}

__device__ __forceinline__ void glds16(const u16* g, u16* l) {
    __builtin_amdgcn_global_load_lds(
        (const __attribute__((address_space(1))) void*)g,
        (__attribute__((address_space(3))) void*)l, 16, 0, 0);
}

// XCD-contiguous swizzle: XCD x = l&7 owns m-tiles [8x, 8x+8) for all n-tiles
// (256-row A panel x8 = 4MB stays resident in that XCD's L2).
__device__ __forceinline__ void swiz8(int l, int& mt, int& nt) {
    mt = (l & 7) * 8 + ((l >> 3) & 7);
    nt = l >> 6;
}

// ---------------------------------------------------------------------------
// NT GEMM: out[m,n] = sum_k A[m,k]*W[n,k] + bias[n].
// BM=256, BN=256, BK=32, 512 threads (8 waves, 2x4 of 128x64).
// 4-deep LDS K-tile ring (128KB), prefetch distance 3, counted vmcnt(12),
// tail peeled at vmcnt(8/4/0). Two barriers per K-tile:
//   B1 (after vmcnt): all lanes' loads for tile kt landed -> safe to ds_read
//   B2 (after MFMA):  all waves' ds_reads of buf[kt&3] done -> safe to restage
// MODE 0: bf16 out via LDS-staged coalesced write
// MODE 2: f32 out = v + bias + auxf[idx]
// ---------------------------------------------------------------------------
template <int MODE>
__global__ __launch_bounds__(512, 2)
void gemm_bt(const u16* __restrict__ A, const u16* __restrict__ Bw,
             const float* __restrict__ bias, const float* __restrict__ auxf,
             u16* __restrict__ outb, float* __restrict__ outf)
{
    __shared__ __align__(16) u16 smem[65536];   // 4 x (A 8192 + B 8192) u16 = 128KB

    int mt, nt; swiz8(blockIdx.x, mt, nt);
    const int m0 = mt * 256, n0 = nt * 256;
    const int tid = threadIdx.x;
    const int wave = tid >> 6, lane = tid & 63;
    const int wm = (wave >> 2) * 128, wn = (wave & 3) * 64;
    const int lr = lane & 15, lq = lane >> 4;

    // staging: thread stages LDS slot (trow, tcol); global k-chunk = tcol ^ ((trow>>1)&3)
    const int trow = tid >> 2, tcol = tid & 3;
    const int kswz = (tcol ^ ((trow >> 1) & 3)) * 8;
    const u16* Ag = A + (size_t)(m0 + trow) * DD + kswz;
    const u16* Bg = Bw + (size_t)(n0 + trow) * DD + kswz;
    const int st = tid * 8;
    const int cs = (lq ^ ((lr >> 1) & 3)) * 8;

    f32x4 acc[8][4] = {};

    auto STAGE = [&](int kt) {
        u16* Ls = smem + (kt & 3) * 16384;
        const u16* a = Ag + (size_t)kt * 32;
        const u16* b = Bg + (size_t)kt * 32;
        glds16(a, Ls + st);
        glds16(a + (size_t)128 * DD, Ls + 4096 + st);
        glds16(b, Ls + 8192 + st);
        glds16(b + (size_t)128 * DD, Ls + 12288 + st);
    };
    auto KSTEP = [&](int kt) {
        const u16* Ls = smem + (kt & 3) * 16384;
        bf16x8 av[8], bv[4];
#pragma unroll
        for (int i = 0; i < 8; i++)
            av[i] = *(const bf16x8*)&Ls[(wm + i * 16 + lr) * 32 + cs];
#pragma unroll
        for (int j = 0; j < 4; j++)
            bv[j] = *(const bf16x8*)&Ls[8192 + (wn + j * 16 + lr) * 32 + cs];
        __builtin_amdgcn_s_setprio(1);
#pragma unroll
        for (int i = 0; i < 8; i++)
#pragma unroll
            for (int j = 0; j < 4; j++)
                acc[i][j] = __builtin_amdgcn_mfma_f32_16x16x32_bf16(
                    av[i], bv[j], acc[i][j], 0, 0, 0);
        __builtin_amdgcn_s_setprio(0);
    };

    // prologue: 3 K-tiles in flight
    STAGE(0); STAGE(1); STAGE(2);
#pragma unroll 4
    for (int kt = 0; kt < 29; ++kt) {
        STAGE(kt + 3);
        asm volatile("s_waitcnt vmcnt(12)\ns_barrier" ::: "memory");
        KSTEP(kt);
        asm volatile("s_barrier" ::: "memory");
    }
    asm volatile("s_waitcnt vmcnt(8)\ns_barrier" ::: "memory");
    KSTEP(29);
    asm volatile("s_barrier" ::: "memory");
    asm volatile("s_waitcnt vmcnt(4)\ns_barrier" ::: "memory");
    KSTEP(30);
    asm volatile("s_barrier" ::: "memory");
    asm volatile("s_waitcnt vmcnt(0)\ns_barrier" ::: "memory");
    KSTEP(31);

    // epilogue: C/D layout col=lane&15, row=(lane>>4)*4+reg
    if constexpr (MODE == 0) {
        u16* ep = smem;                      // 64 x EPAD2 staging (33KB, reuse ring)
        for (int h = 0; h < 4; ++h) {        // 64-row quarters
            __syncthreads();
            if (wm == (h >> 1) * 128) {
                const int i0 = (h & 1) * 4;
#pragma unroll
                for (int ii = 0; ii < 4; ++ii) {
                    const int i = i0 + ii;
#pragma unroll
                    for (int j = 0; j < 4; ++j) {
                        const int col = wn + j * 16 + lr;
                        const float bz = bias[n0 + col];
#pragma unroll
                        for (int p = 0; p < 4; ++p)
                            ep[(ii * 16 + lq * 4 + p) * EPAD2 + col] =
                                f2b(acc[i][j][p] + bz);
                    }
                }
            }
            __syncthreads();
#pragma unroll
            for (int t = 0; t < 4; ++t) {
                const int f = t * 512 + tid;
                const int row = f >> 5, c8 = (f & 31) * 8;
                *(uint4*)&outb[(size_t)(m0 + h * 64 + row) * DD + n0 + c8] =
                    *(const uint4*)&ep[row * EPAD2 + c8];
            }
        }
    } else {
#pragma unroll
        for (int i = 0; i < 8; ++i) {
            const int mrow = m0 + wm + i * 16 + lq * 4;
#pragma unroll
            for (int j = 0; j < 4; ++j) {
                const int ncol = n0 + wn + j * 16 + lr;
                const float bz = bias[ncol];
#pragma unroll
                for (int p = 0; p < 4; ++p) {
                    const size_t idx = (size_t)(mrow + p) * DD + ncol;
                    outf[idx] = acc[i][j][p] + bz + auxf[idx];
                }
            }
        }
    }
}

// ---------------------------------------------------------------------------
// Dual GEMM (same A, two W). BM=256, BN=128, BK=32, 512 threads (8 waves,
// 2x4 of 128x32 per GEMM). Same 4-deep ring / vmcnt(12) schedule (4 loads
// per thread per K-tile: A x2 rounds, B1 x1, B2 x1).
// DMODE 0: out1 = sigmoid(A@B1^T+b1), out2 = sigmoid(A@B2^T+b2)  (rt, it)
// DMODE 1: out1 = gelu(sigmoid(A@B1^T+b1)) * (A@B2^T+b2)         (combined)
// ---------------------------------------------------------------------------
template <int DMODE>
__global__ __launch_bounds__(512, 2)
void gemm_dual(const u16* __restrict__ A, const u16* __restrict__ B1,
               const u16* __restrict__ B2,
               const float* __restrict__ bias1, const float* __restrict__ bias2,
               u16* __restrict__ out1, u16* __restrict__ out2)
{
    __shared__ __align__(16) u16 smem[65536];  // 4 x (A 8192 + B1 4096 + B2 4096)

    int mt, nt; swiz8(blockIdx.x, mt, nt);
    const int m0 = mt * 256, n0 = nt * 128;
    const int tid = threadIdx.x;
    const int wave = tid >> 6, lane = tid & 63;
    const int wm = (wave >> 2) * 128, wn = (wave & 3) * 32;
    const int lr = lane & 15, lq = lane >> 4;

    const int trow = tid >> 2, tcol = tid & 3;
    const int kswz = (tcol ^ ((trow >> 1) & 3)) * 8;
    const u16* Ag  = A  + (size_t)(m0 + trow) * DD + kswz;
    const u16* B1g = B1 + (size_t)(n0 + trow) * DD + kswz;
    const u16* B2g = B2 + (size_t)(n0 + trow) * DD + kswz;
    const int st = tid * 8;
    const int cs = (lq ^ ((lr >> 1) & 3)) * 8;

    f32x4 acc1[8][2] = {}, acc2[8][2] = {};

    auto STAGE = [&](int kt) {
        u16* Ls = smem + (kt & 3) * 16384;
        const u16* a = Ag + (size_t)kt * 32;
        glds16(a, Ls + st);
        glds16(a + (size_t)128 * DD, Ls + 4096 + st);
        glds16(B1g + (size_t)kt * 32, Ls + 8192 + st);
        glds16(B2g + (size_t)kt * 32, Ls + 12288 + st);
    };
    auto KSTEP = [&](int kt) {
        const u16* Ls = smem + (kt & 3) * 16384;
        bf16x8 av[8], bv1[2], bv2[2];
#pragma unroll
        for (int i = 0; i < 8; i++)
            av[i] = *(const bf16x8*)&Ls[(wm + i * 16 + lr) * 32 + cs];
#pragma unroll
        for (int j = 0; j < 2; j++) {
            bv1[j] = *(const bf16x8*)&Ls[8192 + (wn + j * 16 + lr) * 32 + cs];
            bv2[j] = *(const bf16x8*)&Ls[12288 + (wn + j * 16 + lr) * 32 + cs];
        }
        __builtin_amdgcn_s_setprio(1);
#pragma unroll
        for (int i = 0; i < 8; i++)
#pragma unroll
            for (int j = 0; j < 2; j++) {
                acc1[i][j] = __builtin_amdgcn_mfma_f32_16x16x32_bf16(
                    av[i], bv1[j], acc1[i][j], 0, 0, 0);
                acc2[i][j] = __builtin_amdgcn_mfma_f32_16x16x32_bf16(
                    av[i], bv2[j], acc2[i][j], 0, 0, 0);
            }
        __builtin_amdgcn_s_setprio(0);
    };

    STAGE(0); STAGE(1); STAGE(2);
#pragma unroll 4
    for (int kt = 0; kt < 29; ++kt) {
        STAGE(kt + 3);
        asm volatile("s_waitcnt vmcnt(12)\ns_barrier" ::: "memory");
        KSTEP(kt);
        asm volatile("s_barrier" ::: "memory");
    }
    asm volatile("s_waitcnt vmcnt(8)\ns_barrier" ::: "memory");
    KSTEP(29);
    asm volatile("s_barrier" ::: "memory");
    asm volatile("s_waitcnt vmcnt(4)\ns_barrier" ::: "memory");
    KSTEP(30);
    asm volatile("s_barrier" ::: "memory");
    asm volatile("s_waitcnt vmcnt(0)\ns_barrier" ::: "memory");
    KSTEP(31);

    u16* ep = smem;                          // 64 x EPAD staging, reuse ring
    if constexpr (DMODE == 0) {
#pragma unroll
        for (int o = 0; o < 2; ++o) {
            const float* bz = o ? bias2 : bias1;
            u16* op = o ? out2 : out1;
            for (int h = 0; h < 4; ++h) {
                __syncthreads();
                if (wm == (h >> 1) * 128) {
                    const int i0 = (h & 1) * 4;
#pragma unroll
                    for (int ii = 0; ii < 4; ++ii) {
                        const int i = i0 + ii;
#pragma unroll
                        for (int j = 0; j < 2; ++j) {
                            const int col = wn + j * 16 + lr;
                            const float bb = bz[n0 + col];
#pragma unroll
                            for (int p = 0; p < 4; ++p) {
                                const float v = (o ? acc2[i][j][p] : acc1[i][j][p]) + bb;
                                ep[(ii * 16 + lq * 4 + p) * EPAD + col] = f2b(sigmoid_f(v));
                            }
                        }
                    }
                }
                __syncthreads();
#pragma unroll
                for (int t = 0; t < 2; ++t) {
                    const int f = t * 512 + tid;
                    const int row = f >> 4, c8 = (f & 15) * 8;
                    *(uint4*)&op[(size_t)(m0 + h * 64 + row) * DD + n0 + c8] =
                        *(const uint4*)&ep[row * EPAD + c8];
                }
            }
        }
    } else {
        for (int h = 0; h < 4; ++h) {
            __syncthreads();
            if (wm == (h >> 1) * 128) {
                const int i0 = (h & 1) * 4;
#pragma unroll
                for (int ii = 0; ii < 4; ++ii) {
                    const int i = i0 + ii;
#pragma unroll
                    for (int j = 0; j < 2; ++j) {
                        const int col = wn + j * 16 + lr;
                        const float bb1 = bias1[n0 + col];
                        const float bb2 = bias2[n0 + col];
#pragma unroll
                        for (int p = 0; p < 4; ++p) {
                            const float g = gelu_f(sigmoid_f(acc1[i][j][p] + bb1));
                            ep[(ii * 16 + lq * 4 + p) * EPAD + col] =
                                f2b(g * (acc2[i][j][p] + bb2));
                        }
                    }
                }
            }
            __syncthreads();
#pragma unroll
            for (int t = 0; t < 2; ++t) {
                const int f = t * 512 + tid;
                const int row = f >> 4, c8 = (f & 15) * 8;
                *(uint4*)&out1[(size_t)(m0 + h * 64 + row) * DD + n0 + c8] =
                    *(const uint4*)&ep[row * EPAD + c8];
            }
        }
    }
}

// ---------------------------------------------------------------------------
// RMSNorm: one block per row; out bf16 = x/max(||x||,1e-12)*sqrt(D)*g
// ---------------------------------------------------------------------------
__global__ __launch_bounds__(256)
void rmsnorm_k(const float* __restrict__ x, const float* __restrict__ g,
               u16* __restrict__ out)
{
    const int row = blockIdx.x;
    const int t = threadIdx.x;
    const float4 v = ((const float4*)(x + (size_t)row * DD))[t];
    float ss = v.x * v.x + v.y * v.y + v.z * v.z + v.w * v.w;
#pragma unroll
    for (int o = 32; o > 0; o >>= 1) ss += __shfl_down(ss, o, 64);
    __shared__ float wsum[4];
    if ((t & 63) == 0) wsum[t >> 6] = ss;
    __syncthreads();
    const float tot = wsum[0] + wsum[1] + wsum[2] + wsum[3];
    const float sc = 32.0f * rsqrtf(fmaxf(tot, 1e-24f));
    const float4 gv = ((const float4*)g)[t];
    ushort4 o4;
    o4.x = f2b(v.x * sc * gv.x);
    o4.y = f2b(v.y * sc * gv.y);
    o4.z = f2b(v.z * sc * gv.z);
    o4.w = f2b(v.w * sc * gv.w);
    ((ushort4*)(out + (size_t)row * DD))[t] = o4;
}

// ---------------------------------------------------------------------------
// fp32 -> bf16 conversion of all 8 weight matrices in one launch
// ---------------------------------------------------------------------------
struct W8 { const float* s[8]; };
__global__ __launch_bounds__(256)
void conv_w8(W8 w, u16* __restrict__ out)
{
    const float* in = w.s[blockIdx.y];
    u16* o = out + (size_t)blockIdx.y * DD * DD;
    const int i = (blockIdx.x * 256 + threadIdx.x) * 4;
    const float4 v = *(const float4*)(in + i);
    ushort4 r;
    r.x = f2b(v.x); r.y = f2b(v.y); r.z = f2b(v.z); r.w = f2b(v.w);
    *(ushort4*)(o + i) = r;
}

// ---------------------------------------------------------------------------
// RG-LRU chunked scan. h[t] = a[t]*h[t-1] + g[t]
// a = exp(log_a * rt / 8), log_a = -softplus(-Lam[d])
// g = sqrt(1-a^2) * it * x_rg
// ---------------------------------------------------------------------------
__global__ __launch_bounds__(256)
void scan_chunks(const u16* __restrict__ rt, const u16* __restrict__ it,
                 const u16* __restrict__ rg, const float* __restrict__ Lam,
                 float* __restrict__ P, float* __restrict__ Hl)
{
    const int d = blockIdx.x * 256 + threadIdx.x;
    const int c = blockIdx.y, b = blockIdx.z;
    const float k = -log1pf(__expf(-Lam[d])) * 0.125f;
    const size_t base = (((size_t)b * 4096) + (size_t)c * CLEN) * DD + d;
    float p = 1.f, h = 0.f;
#pragma unroll 4
    for (int t = 0; t < CLEN; t++) {
        const size_t ix = base + (size_t)t * DD;
        const float r = b2f(rt[ix]);
        const float i = b2f(it[ix]);
        const float xv = b2f(rg[ix]);
        const float a = __expf(k * r);
        const float g = sqrtf(fmaxf(1.f - a * a, 0.f)) * (i * xv);
        p *= a;
        h = fmaf(a, h, g);
    }
    const int o = (b * NCH + c) * DD + d;
    P[o] = p;
    Hl[o] = h;
}

__global__ __launch_bounds__(256)
void scan_carry(const float* __restrict__ P, const float* __restrict__ Hl,
                float* __restrict__ Cin)
{
    const int idx = blockIdx.x * 256 + threadIdx.x;  // B*D = 4096
    const int b = idx >> 10, d = idx & 1023;
    float h = 0.f;
    for (int c = 0; c < NCH; c++) {
        const int o = (b * NCH + c) * DD + d;
        Cin[o] = h;
        h = fmaf(P[o], h, Hl[o]);
    }
}

__global__ __launch_bounds__(256)
void scan_apply(const u16* __restrict__ rt, const u16* __restrict__ it,
                const u16* __restrict__ rg, const u16* __restrict__ lin,
                const float* __restrict__ Lam, const float* __restrict__ Cin,
                u16* __restrict__ yin)
{
    const int d = blockIdx.x * 256 + threadIdx.x;
    const int c = blockIdx.y, b = blockIdx.z;
    const float k = -log1pf(__expf(-Lam[d])) * 0.125f;
    const size_t base = (((size_t)b * 4096) + (size_t)c * CLEN) * DD + d;
    float h = Cin[(b * NCH + c) * DD + d];
#pragma unroll 4
    for (int t = 0; t < CLEN; t++) {
        const size_t ix = base + (size_t)t * DD;
        const float r = b2f(rt[ix]);
        const float i = b2f(it[ix]);
        const float xv = b2f(rg[ix]);
        const float a = __expf(k * r);
        const float g = sqrtf(fmaxf(1.f - a * a, 0.f)) * (i * xv);
        h = fmaf(a, h, g);
        const float l = b2f(lin[ix]);
        yin[ix] = f2b(gelu_f(l) * h);
    }
}

// ---------------------------------------------------------------------------
extern "C" void kernel_launch(void* const* d_in, const int* in_sizes, int n_in,
                              void* d_out, int out_size, void* d_ws, size_t ws_size,
                              hipStream_t stream)
{
    const float* x      = (const float*)d_in[0];
    const float* g1     = (const float*)d_in[1];
    const float* g2     = (const float*)d_in[2];
    const float* W_lin  = (const float*)d_in[3];
    const float* b_lin  = (const float*)d_in[4];
    const float* W_conv = (const float*)d_in[5];
    const float* b_conv = (const float*)d_in[6];
    const float* W_lin2 = (const float*)d_in[7];
    const float* b_lin2 = (const float*)d_in[8];
    const float* Wa     = (const float*)d_in[9];
    const float* ba     = (const float*)d_in[10];
    const float* Wx     = (const float*)d_in[11];
    const float* bx     = (const float*)d_in[12];
    const float* Lam    = (const float*)d_in[13];
    const float* W1     = (const float*)d_in[14];
    const float* b1     = (const float*)d_in[15];
    const float* W2     = (const float*)d_in[16];
    const float* b2     = (const float*)d_in[17];
    const float* W3     = (const float*)d_in[18];
    const float* b3     = (const float*)d_in[19];
    float* out = (float*)d_out;

    char* p = (char*)d_ws;
    auto alloc = [&](size_t bytes) -> char* {
        char* q = p;
        p += (bytes + 255) & ~(size_t)255;
        return q;
    };
    const size_t MD = (size_t)MM * DD;
    u16* wball = (u16*)alloc((size_t)8 * DD * DD * 2);
    u16* t0 = (u16*)alloc(MD * 2);
    u16* t1 = (u16*)alloc(MD * 2);
    u16* t2 = (u16*)alloc(MD * 2);
    u16* t3 = (u16*)alloc(MD * 2);
    u16* t4 = (u16*)alloc(MD * 2);
    float* res2 = (float*)alloc(MD * 4);
    float* P   = (float*)alloc((size_t)4 * NCH * DD * 4);
    float* Hl  = (float*)alloc((size_t)4 * NCH * DD * 4);
    float* Cin = (float*)alloc((size_t)4 * NCH * DD * 4);

    // weights -> bf16 (order: W_lin, W_conv, Wa, Wx, W_lin2, W1, W2, W3)
    W8 w8;
    w8.s[0] = W_lin; w8.s[1] = W_conv; w8.s[2] = Wa; w8.s[3] = Wx;
    w8.s[4] = W_lin2; w8.s[5] = W1; w8.s[6] = W2; w8.s[7] = W3;
    conv_w8<<<dim3(DD * DD / 1024, 8), 256, 0, stream>>>(w8, wball);
    u16* wbf[8];
    for (int i = 0; i < 8; i++) wbf[i] = wball + (size_t)i * DD * DD;

    const int gs = (MM / 256) * (DD / 256);   // 256 blocks (single GEMM)
    const int gd = (MM / 256) * (DD / 128);   // 512 blocks (dual GEMM)
    const dim3 sg(DD / 256, NCH, 4);

    // xn = rmsnorm(x)*g1
    rmsnorm_k<<<MM, 256, 0, stream>>>(x, g1, t0);
    // lin = xn@W_lin.T + b_lin
    gemm_bt<0><<<gs, 512, 0, stream>>>(t0, wbf[0], b_lin, nullptr, t1, nullptr);
    // rg = lin@W_conv.T + b_conv
    gemm_bt<0><<<gs, 512, 0, stream>>>(t1, wbf[1], b_conv, nullptr, t2, nullptr);
    // rt = sigmoid(rg@Wa.T + ba), it = sigmoid(rg@Wx.T + bx)
    gemm_dual<0><<<gd, 512, 0, stream>>>(t2, wbf[2], wbf[3], ba, bx, t0, t3);
    // RG-LRU scan + yin = gelu(lin)*h
    scan_chunks<<<sg, 256, 0, stream>>>(t0, t3, t2, Lam, P, Hl);
    scan_carry<<<4096 / 256, 256, 0, stream>>>(P, Hl, Cin);
    scan_apply<<<sg, 256, 0, stream>>>(t0, t3, t2, t1, Lam, Cin, t4);
    // res2 = yin@W_lin2.T + b_lin2 + x
    gemm_bt<2><<<gs, 512, 0, stream>>>(t4, wbf[4], b_lin2, x, nullptr, res2);
    // xm = rmsnorm(res2)*g2
    rmsnorm_k<<<MM, 256, 0, stream>>>(res2, g2, t0);
    // combined = gelu(sigmoid(xm@W1.T+b1)) * (xm@W2.T+b2)
    gemm_dual<1><<<gd, 512, 0, stream>>>(t0, wbf[5], wbf[6], b1, b2, t2, nullptr);
    // y = combined@W3.T + b3 + res2
    gemm_bt<2><<<gs, 512, 0, stream>>>(t2, wbf[7], b3, res2, nullptr, out);
}

// Round 2
// 637.577 us; speedup vs baseline: 5.1639x; 5.1639x over previous
//
#include <hip/hip_runtime.h>
#include <cstdint>
#include <cstddef>

typedef unsigned short u16;
typedef __attribute__((ext_vector_type(8))) __bf16 bf16x8;
typedef __attribute__((ext_vector_type(4))) float f32x4;

#define DD 1024            // D
#define MM 16384           // B*T rows
#define NCH 64             // scan chunks
#define CLEN 64            // chunk length (NCH*CLEN = T = 4096)
#define EPAD 136           // epilogue LDS row stride (128-col tiles), u16
#define EPAD2 264          // epilogue LDS row stride (256-col tiles), u16

__device__ __forceinline__ u16 f2b(float f) {
    uint32_t u = __float_as_uint(f);
    u += 0x7fffu + ((u >> 16) & 1u);       // round-to-nearest-even
    return (u16)(u >> 16);
}
__device__ __forceinline__ float b2f(u16 v) {
    return __uint_as_float(((uint32_t)v) << 16);
}
__device__ __forceinline__ float sigmoid_f(float v) { return 1.f / (1.f + __expf(-v)); }
__device__ __forceinline__ float gelu_f(float v) {
    return 0.5f * v * (1.f + erff(v * 0.70710678118654752f));
}

__device__ __forceinline__ void glds16(const u16* g, u16* l) {
    __builtin_amdgcn_global_load_lds(
        (const __attribute__((address_space(1))) void*)g,
        (__attribute__((address_space(3))) void*)l, 16, 0, 0);
}

// XCD-contiguous swizzle: XCD x = l&7 owns m-tiles [8x, 8x+8) for all n-tiles
// (256-row A panel x8 = 4MB stays resident in that XCD's L2).
__device__ __forceinline__ void swiz8(int l, int& mt, int& nt) {
    mt = (l & 7) * 8 + ((l >> 3) & 7);
    nt = l >> 6;
}

// ---------------------------------------------------------------------------
// NT GEMM: out[m,n] = sum_k A[m,k]*W[n,k] + bias[n].
// BM=256, BN=256, BK=32, 512 threads (8 waves, 2x4 of 128x64).
// 4-deep LDS K-tile ring (128KB), prefetch distance 3, counted vmcnt(12),
// tail peeled at vmcnt(8/4/0). Two barriers per K-tile.
// NOTE: every epilogue loop that indexes acc[] MUST be #pragma unroll'd —
// a runtime index demotes the whole accumulator array to scratch (rule #20;
// round-1 post-mortem: 4.4GB of spill writes per dispatch).
// MODE 0: bf16 out via LDS-staged coalesced write
// MODE 2: f32 out = v + bias + auxf[idx]
// ---------------------------------------------------------------------------
template <int MODE>
__global__ __launch_bounds__(512, 2)
void gemm_bt(const u16* __restrict__ A, const u16* __restrict__ Bw,
             const float* __restrict__ bias, const float* __restrict__ auxf,
             u16* __restrict__ outb, float* __restrict__ outf)
{
    __shared__ __align__(16) u16 smem[65536];   // 4 x (A 8192 + B 8192) u16 = 128KB

    int mt, nt; swiz8(blockIdx.x, mt, nt);
    const int m0 = mt * 256, n0 = nt * 256;
    const int tid = threadIdx.x;
    const int wave = tid >> 6, lane = tid & 63;
    const int wm = (wave >> 2) * 128, wn = (wave & 3) * 64;
    const int lr = lane & 15, lq = lane >> 4;

    // staging: thread stages LDS slot (trow, tcol); global k-chunk = tcol ^ ((trow>>1)&3)
    const int trow = tid >> 2, tcol = tid & 3;
    const int kswz = (tcol ^ ((trow >> 1) & 3)) * 8;
    const u16* Ag = A + (size_t)(m0 + trow) * DD + kswz;
    const u16* Bg = Bw + (size_t)(n0 + trow) * DD + kswz;
    const int st = tid * 8;
    const int cs = (lq ^ ((lr >> 1) & 3)) * 8;

    f32x4 acc[8][4] = {};

    auto STAGE = [&](int kt) {
        u16* Ls = smem + (kt & 3) * 16384;
        const u16* a = Ag + (size_t)kt * 32;
        const u16* b = Bg + (size_t)kt * 32;
        glds16(a, Ls + st);
        glds16(a + (size_t)128 * DD, Ls + 4096 + st);
        glds16(b, Ls + 8192 + st);
        glds16(b + (size_t)128 * DD, Ls + 12288 + st);
    };
    auto KSTEP = [&](int kt) {
        const u16* Ls = smem + (kt & 3) * 16384;
        bf16x8 av[8], bv[4];
#pragma unroll
        for (int i = 0; i < 8; i++)
            av[i] = *(const bf16x8*)&Ls[(wm + i * 16 + lr) * 32 + cs];
#pragma unroll
        for (int j = 0; j < 4; j++)
            bv[j] = *(const bf16x8*)&Ls[8192 + (wn + j * 16 + lr) * 32 + cs];
        __builtin_amdgcn_s_setprio(1);
#pragma unroll
        for (int i = 0; i < 8; i++)
#pragma unroll
            for (int j = 0; j < 4; j++)
                acc[i][j] = __builtin_amdgcn_mfma_f32_16x16x32_bf16(
                    av[i], bv[j], acc[i][j], 0, 0, 0);
        __builtin_amdgcn_s_setprio(0);
    };

    // prologue: 3 K-tiles in flight
    STAGE(0); STAGE(1); STAGE(2);
#pragma unroll 4
    for (int kt = 0; kt < 29; ++kt) {
        STAGE(kt + 3);
        asm volatile("s_waitcnt vmcnt(12)\ns_barrier" ::: "memory");
        KSTEP(kt);
        asm volatile("s_barrier" ::: "memory");
    }
    asm volatile("s_waitcnt vmcnt(8)\ns_barrier" ::: "memory");
    KSTEP(29);
    asm volatile("s_barrier" ::: "memory");
    asm volatile("s_waitcnt vmcnt(4)\ns_barrier" ::: "memory");
    KSTEP(30);
    asm volatile("s_barrier" ::: "memory");
    asm volatile("s_waitcnt vmcnt(0)\ns_barrier" ::: "memory");
    KSTEP(31);

    // epilogue: C/D layout col=lane&15, row=(lane>>4)*4+reg
    if constexpr (MODE == 0) {
        u16* ep = smem;                      // 64 x EPAD2 staging (33KB, reuse ring)
#pragma unroll                               // h MUST be compile-time: acc[i0+ii] index
        for (int h = 0; h < 4; ++h) {        // 64-row quarters
            __syncthreads();
            if (wm == (h >> 1) * 128) {
                const int i0 = (h & 1) * 4;
#pragma unroll
                for (int ii = 0; ii < 4; ++ii) {
                    const int i = i0 + ii;
#pragma unroll
                    for (int j = 0; j < 4; ++j) {
                        const int col = wn + j * 16 + lr;
                        const float bz = bias[n0 + col];
#pragma unroll
                        for (int p = 0; p < 4; ++p)
                            ep[(ii * 16 + lq * 4 + p) * EPAD2 + col] =
                                f2b(acc[i][j][p] + bz);
                    }
                }
            }
            __syncthreads();
#pragma unroll
            for (int t = 0; t < 4; ++t) {
                const int f = t * 512 + tid;
                const int row = f >> 5, c8 = (f & 31) * 8;
                *(uint4*)&outb[(size_t)(m0 + h * 64 + row) * DD + n0 + c8] =
                    *(const uint4*)&ep[row * EPAD2 + c8];
            }
        }
    } else {
#pragma unroll
        for (int i = 0; i < 8; ++i) {
            const int mrow = m0 + wm + i * 16 + lq * 4;
#pragma unroll
            for (int j = 0; j < 4; ++j) {
                const int ncol = n0 + wn + j * 16 + lr;
                const float bz = bias[ncol];
#pragma unroll
                for (int p = 0; p < 4; ++p) {
                    const size_t idx = (size_t)(mrow + p) * DD + ncol;
                    outf[idx] = acc[i][j][p] + bz + auxf[idx];
                }
            }
        }
    }
}

// ---------------------------------------------------------------------------
// Dual GEMM (same A, two W). BM=256, BN=128, BK=32, 512 threads (8 waves,
// 2x4 of 128x32 per GEMM). Same 4-deep ring / vmcnt(12) schedule (4 loads
// per thread per K-tile: A x2 rounds, B1 x1, B2 x1).
// DMODE 0: out1 = sigmoid(A@B1^T+b1), out2 = sigmoid(A@B2^T+b2)  (rt, it)
// DMODE 1: out1 = gelu(sigmoid(A@B1^T+b1)) * (A@B2^T+b2)         (combined)
// ---------------------------------------------------------------------------
template <int DMODE>
__global__ __launch_bounds__(512, 2)
void gemm_dual(const u16* __restrict__ A, const u16* __restrict__ B1,
               const u16* __restrict__ B2,
               const float* __restrict__ bias1, const float* __restrict__ bias2,
               u16* __restrict__ out1, u16* __restrict__ out2)
{
    __shared__ __align__(16) u16 smem[65536];  // 4 x (A 8192 + B1 4096 + B2 4096)

    int mt, nt; swiz8(blockIdx.x, mt, nt);
    const int m0 = mt * 256, n0 = nt * 128;
    const int tid = threadIdx.x;
    const int wave = tid >> 6, lane = tid & 63;
    const int wm = (wave >> 2) * 128, wn = (wave & 3) * 32;
    const int lr = lane & 15, lq = lane >> 4;

    const int trow = tid >> 2, tcol = tid & 3;
    const int kswz = (tcol ^ ((trow >> 1) & 3)) * 8;
    const u16* Ag  = A  + (size_t)(m0 + trow) * DD + kswz;
    const u16* B1g = B1 + (size_t)(n0 + trow) * DD + kswz;
    const u16* B2g = B2 + (size_t)(n0 + trow) * DD + kswz;
    const int st = tid * 8;
    const int cs = (lq ^ ((lr >> 1) & 3)) * 8;

    f32x4 acc1[8][2] = {}, acc2[8][2] = {};

    auto STAGE = [&](int kt) {
        u16* Ls = smem + (kt & 3) * 16384;
        const u16* a = Ag + (size_t)kt * 32;
        glds16(a, Ls + st);
        glds16(a + (size_t)128 * DD, Ls + 4096 + st);
        glds16(B1g + (size_t)kt * 32, Ls + 8192 + st);
        glds16(B2g + (size_t)kt * 32, Ls + 12288 + st);
    };
    auto KSTEP = [&](int kt) {
        const u16* Ls = smem + (kt & 3) * 16384;
        bf16x8 av[8], bv1[2], bv2[2];
#pragma unroll
        for (int i = 0; i < 8; i++)
            av[i] = *(const bf16x8*)&Ls[(wm + i * 16 + lr) * 32 + cs];
#pragma unroll
        for (int j = 0; j < 2; j++) {
            bv1[j] = *(const bf16x8*)&Ls[8192 + (wn + j * 16 + lr) * 32 + cs];
            bv2[j] = *(const bf16x8*)&Ls[12288 + (wn + j * 16 + lr) * 32 + cs];
        }
        __builtin_amdgcn_s_setprio(1);
#pragma unroll
        for (int i = 0; i < 8; i++)
#pragma unroll
            for (int j = 0; j < 2; j++) {
                acc1[i][j] = __builtin_amdgcn_mfma_f32_16x16x32_bf16(
                    av[i], bv1[j], acc1[i][j], 0, 0, 0);
                acc2[i][j] = __builtin_amdgcn_mfma_f32_16x16x32_bf16(
                    av[i], bv2[j], acc2[i][j], 0, 0, 0);
            }
        __builtin_amdgcn_s_setprio(0);
    };

    STAGE(0); STAGE(1); STAGE(2);
#pragma unroll 4
    for (int kt = 0; kt < 29; ++kt) {
        STAGE(kt + 3);
        asm volatile("s_waitcnt vmcnt(12)\ns_barrier" ::: "memory");
        KSTEP(kt);
        asm volatile("s_barrier" ::: "memory");
    }
    asm volatile("s_waitcnt vmcnt(8)\ns_barrier" ::: "memory");
    KSTEP(29);
    asm volatile("s_barrier" ::: "memory");
    asm volatile("s_waitcnt vmcnt(4)\ns_barrier" ::: "memory");
    KSTEP(30);
    asm volatile("s_barrier" ::: "memory");
    asm volatile("s_waitcnt vmcnt(0)\ns_barrier" ::: "memory");
    KSTEP(31);

    u16* ep = smem;                          // 64 x EPAD staging, reuse ring
    if constexpr (DMODE == 0) {
#pragma unroll
        for (int o = 0; o < 2; ++o) {
            const float* bz = o ? bias2 : bias1;
            u16* op = o ? out2 : out1;
#pragma unroll                               // h MUST be compile-time (rule #20)
            for (int h = 0; h < 4; ++h) {
                __syncthreads();
                if (wm == (h >> 1) * 128) {
                    const int i0 = (h & 1) * 4;
#pragma unroll
                    for (int ii = 0; ii < 4; ++ii) {
                        const int i = i0 + ii;
#pragma unroll
                        for (int j = 0; j < 2; ++j) {
                            const int col = wn + j * 16 + lr;
                            const float bb = bz[n0 + col];
#pragma unroll
                            for (int p = 0; p < 4; ++p) {
                                const float v = (o ? acc2[i][j][p] : acc1[i][j][p]) + bb;
                                ep[(ii * 16 + lq * 4 + p) * EPAD + col] = f2b(sigmoid_f(v));
                            }
                        }
                    }
                }
                __syncthreads();
#pragma unroll
                for (int t = 0; t < 2; ++t) {
                    const int f = t * 512 + tid;
                    const int row = f >> 4, c8 = (f & 15) * 8;
                    *(uint4*)&op[(size_t)(m0 + h * 64 + row) * DD + n0 + c8] =
                        *(const uint4*)&ep[row * EPAD + c8];
                }
            }
        }
    } else {
#pragma unroll                               // h MUST be compile-time (rule #20)
        for (int h = 0; h < 4; ++h) {
            __syncthreads();
            if (wm == (h >> 1) * 128) {
                const int i0 = (h & 1) * 4;
#pragma unroll
                for (int ii = 0; ii < 4; ++ii) {
                    const int i = i0 + ii;
#pragma unroll
                    for (int j = 0; j < 2; ++j) {
                        const int col = wn + j * 16 + lr;
                        const float bb1 = bias1[n0 + col];
                        const float bb2 = bias2[n0 + col];
#pragma unroll
                        for (int p = 0; p < 4; ++p) {
                            const float g = gelu_f(sigmoid_f(acc1[i][j][p] + bb1));
                            ep[(ii * 16 + lq * 4 + p) * EPAD + col] =
                                f2b(g * (acc2[i][j][p] + bb2));
                        }
                    }
                }
            }
            __syncthreads();
#pragma unroll
            for (int t = 0; t < 2; ++t) {
                const int f = t * 512 + tid;
                const int row = f >> 4, c8 = (f & 15) * 8;
                *(uint4*)&out1[(size_t)(m0 + h * 64 + row) * DD + n0 + c8] =
                    *(const uint4*)&ep[row * EPAD + c8];
            }
        }
    }
}

// ---------------------------------------------------------------------------
// RMSNorm: one block per row; out bf16 = x/max(||x||,1e-12)*sqrt(D)*g
// ---------------------------------------------------------------------------
__global__ __launch_bounds__(256)
void rmsnorm_k(const float* __restrict__ x, const float* __restrict__ g,
               u16* __restrict__ out)
{
    const int row = blockIdx.x;
    const int t = threadIdx.x;
    const float4 v = ((const float4*)(x + (size_t)row * DD))[t];
    float ss = v.x * v.x + v.y * v.y + v.z * v.z + v.w * v.w;
#pragma unroll
    for (int o = 32; o > 0; o >>= 1) ss += __shfl_down(ss, o, 64);
    __shared__ float wsum[4];
    if ((t & 63) == 0) wsum[t >> 6] = ss;
    __syncthreads();
    const float tot = wsum[0] + wsum[1] + wsum[2] + wsum[3];
    const float sc = 32.0f * rsqrtf(fmaxf(tot, 1e-24f));
    const float4 gv = ((const float4*)g)[t];
    ushort4 o4;
    o4.x = f2b(v.x * sc * gv.x);
    o4.y = f2b(v.y * sc * gv.y);
    o4.z = f2b(v.z * sc * gv.z);
    o4.w = f2b(v.w * sc * gv.w);
    ((ushort4*)(out + (size_t)row * DD))[t] = o4;
}

// ---------------------------------------------------------------------------
// fp32 -> bf16 conversion of all 8 weight matrices in one launch
// ---------------------------------------------------------------------------
struct W8 { const float* s[8]; };
__global__ __launch_bounds__(256)
void conv_w8(W8 w, u16* __restrict__ out)
{
    const float* in = w.s[blockIdx.y];
    u16* o = out + (size_t)blockIdx.y * DD * DD;
    const int i = (blockIdx.x * 256 + threadIdx.x) * 4;
    const float4 v = *(const float4*)(in + i);
    ushort4 r;
    r.x = f2b(v.x); r.y = f2b(v.y); r.z = f2b(v.z); r.w = f2b(v.w);
    *(ushort4*)(o + i) = r;
}

// ---------------------------------------------------------------------------
// RG-LRU chunked scan. h[t] = a[t]*h[t-1] + g[t]
// a = exp(log_a * rt / 8), log_a = -softplus(-Lam[d])
// g = sqrt(1-a^2) * it * x_rg
// ---------------------------------------------------------------------------
__global__ __launch_bounds__(256)
void scan_chunks(const u16* __restrict__ rt, const u16* __restrict__ it,
                 const u16* __restrict__ rg, const float* __restrict__ Lam,
                 float* __restrict__ P, float* __restrict__ Hl)
{
    const int d = blockIdx.x * 256 + threadIdx.x;
    const int c = blockIdx.y, b = blockIdx.z;
    const float k = -log1pf(__expf(-Lam[d])) * 0.125f;
    const size_t base = (((size_t)b * 4096) + (size_t)c * CLEN) * DD + d;
    float p = 1.f, h = 0.f;
#pragma unroll 4
    for (int t = 0; t < CLEN; t++) {
        const size_t ix = base + (size_t)t * DD;
        const float r = b2f(rt[ix]);
        const float i = b2f(it[ix]);
        const float xv = b2f(rg[ix]);
        const float a = __expf(k * r);
        const float g = sqrtf(fmaxf(1.f - a * a, 0.f)) * (i * xv);
        p *= a;
        h = fmaf(a, h, g);
    }
    const int o = (b * NCH + c) * DD + d;
    P[o] = p;
    Hl[o] = h;
}

__global__ __launch_bounds__(256)
void scan_carry(const float* __restrict__ P, const float* __restrict__ Hl,
                float* __restrict__ Cin)
{
    const int idx = blockIdx.x * 256 + threadIdx.x;  // B*D = 4096
    const int b = idx >> 10, d = idx & 1023;
    float h = 0.f;
    for (int c = 0; c < NCH; c++) {
        const int o = (b * NCH + c) * DD + d;
        Cin[o] = h;
        h = fmaf(P[o], h, Hl[o]);
    }
}

__global__ __launch_bounds__(256)
void scan_apply(const u16* __restrict__ rt, const u16* __restrict__ it,
                const u16* __restrict__ rg, const u16* __restrict__ lin,
                const float* __restrict__ Lam, const float* __restrict__ Cin,
                u16* __restrict__ yin)
{
    const int d = blockIdx.x * 256 + threadIdx.x;
    const int c = blockIdx.y, b = blockIdx.z;
    const float k = -log1pf(__expf(-Lam[d])) * 0.125f;
    const size_t base = (((size_t)b * 4096) + (size_t)c * CLEN) * DD + d;
    float h = Cin[(b * NCH + c) * DD + d];
#pragma unroll 4
    for (int t = 0; t < CLEN; t++) {
        const size_t ix = base + (size_t)t * DD;
        const float r = b2f(rt[ix]);
        const float i = b2f(it[ix]);
        const float xv = b2f(rg[ix]);
        const float a = __expf(k * r);
        const float g = sqrtf(fmaxf(1.f - a * a, 0.f)) * (i * xv);
        h = fmaf(a, h, g);
        const float l = b2f(lin[ix]);
        yin[ix] = f2b(gelu_f(l) * h);
    }
}

// ---------------------------------------------------------------------------
extern "C" void kernel_launch(void* const* d_in, const int* in_sizes, int n_in,
                              void* d_out, int out_size, void* d_ws, size_t ws_size,
                              hipStream_t stream)
{
    const float* x      = (const float*)d_in[0];
    const float* g1     = (const float*)d_in[1];
    const float* g2     = (const float*)d_in[2];
    const float* W_lin  = (const float*)d_in[3];
    const float* b_lin  = (const float*)d_in[4];
    const float* W_conv = (const float*)d_in[5];
    const float* b_conv = (const float*)d_in[6];
    const float* W_lin2 = (const float*)d_in[7];
    const float* b_lin2 = (const float*)d_in[8];
    const float* Wa     = (const float*)d_in[9];
    const float* ba     = (const float*)d_in[10];
    const float* Wx     = (const float*)d_in[11];
    const float* bx     = (const float*)d_in[12];
    const float* Lam    = (const float*)d_in[13];
    const float* W1     = (const float*)d_in[14];
    const float* b1     = (const float*)d_in[15];
    const float* W2     = (const float*)d_in[16];
    const float* b2     = (const float*)d_in[17];
    const float* W3     = (const float*)d_in[18];
    const float* b3     = (const float*)d_in[19];
    float* out = (float*)d_out;

    char* p = (char*)d_ws;
    auto alloc = [&](size_t bytes) -> char* {
        char* q = p;
        p += (bytes + 255) & ~(size_t)255;
        return q;
    };
    const size_t MD = (size_t)MM * DD;
    u16* wball = (u16*)alloc((size_t)8 * DD * DD * 2);
    u16* t0 = (u16*)alloc(MD * 2);
    u16* t1 = (u16*)alloc(MD * 2);
    u16* t2 = (u16*)alloc(MD * 2);
    u16* t3 = (u16*)alloc(MD * 2);
    u16* t4 = (u16*)alloc(MD * 2);
    float* res2 = (float*)alloc(MD * 4);
    float* P   = (float*)alloc((size_t)4 * NCH * DD * 4);
    float* Hl  = (float*)alloc((size_t)4 * NCH * DD * 4);
    float* Cin = (float*)alloc((size_t)4 * NCH * DD * 4);

    // weights -> bf16 (order: W_lin, W_conv, Wa, Wx, W_lin2, W1, W2, W3)
    W8 w8;
    w8.s[0] = W_lin; w8.s[1] = W_conv; w8.s[2] = Wa; w8.s[3] = Wx;
    w8.s[4] = W_lin2; w8.s[5] = W1; w8.s[6] = W2; w8.s[7] = W3;
    conv_w8<<<dim3(DD * DD / 1024, 8), 256, 0, stream>>>(w8, wball);
    u16* wbf[8];
    for (int i = 0; i < 8; i++) wbf[i] = wball + (size_t)i * DD * DD;

    const int gs = (MM / 256) * (DD / 256);   // 256 blocks (single GEMM)
    const int gd = (MM / 256) * (DD / 128);   // 512 blocks (dual GEMM)
    const dim3 sg(DD / 256, NCH, 4);

    // xn = rmsnorm(x)*g1
    rmsnorm_k<<<MM, 256, 0, stream>>>(x, g1, t0);
    // lin = xn@W_lin.T + b_lin
    gemm_bt<0><<<gs, 512, 0, stream>>>(t0, wbf[0], b_lin, nullptr, t1, nullptr);
    // rg = lin@W_conv.T + b_conv
    gemm_bt<0><<<gs, 512, 0, stream>>>(t1, wbf[1], b_conv, nullptr, t2, nullptr);
    // rt = sigmoid(rg@Wa.T + ba), it = sigmoid(rg@Wx.T + bx)
    gemm_dual<0><<<gd, 512, 0, stream>>>(t2, wbf[2], wbf[3], ba, bx, t0, t3);
    // RG-LRU scan + yin = gelu(lin)*h
    scan_chunks<<<sg, 256, 0, stream>>>(t0, t3, t2, Lam, P, Hl);
    scan_carry<<<4096 / 256, 256, 0, stream>>>(P, Hl, Cin);
    scan_apply<<<sg, 256, 0, stream>>>(t0, t3, t2, t1, Lam, Cin, t4);
    // res2 = yin@W_lin2.T + b_lin2 + x
    gemm_bt<2><<<gs, 512, 0, stream>>>(t4, wbf[4], b_lin2, x, nullptr, res2);
    // xm = rmsnorm(res2)*g2
    rmsnorm_k<<<MM, 256, 0, stream>>>(res2, g2, t0);
    // combined = gelu(sigmoid(xm@W1.T+b1)) * (xm@W2.T+b2)
    gemm_dual<1><<<gd, 512, 0, stream>>>(t0, wbf[5], wbf[6], b1, b2, t2, nullptr);
    // y = combined@W3.T + b3 + res2
    gemm_bt<2><<<gs, 512, 0, stream>>>(t2, wbf[7], b3, res2, nullptr, out);
}

// Round 4
// 605.789 us; speedup vs baseline: 5.4349x; 1.0525x over previous
//
#include <hip/hip_runtime.h>
#include <cstdint>
#include <cstddef>

typedef unsigned short u16;
typedef __attribute__((ext_vector_type(8))) __bf16 bf16x8;
typedef __attribute__((ext_vector_type(4))) float f32x4;

#define DD 1024            // D
#define MM 16384           // B*T rows
#define NCH 64             // scan chunks
#define CLEN 64            // chunk length (NCH*CLEN = T = 4096)
#define EPAD2 264          // epilogue LDS row stride (256-col bf16 tiles), u16
#define EPADF 260          // epilogue LDS row stride (256-col f32 tiles), f32

__device__ __forceinline__ u16 f2b(float f) {
    uint32_t u = __float_as_uint(f);
    u += 0x7fffu + ((u >> 16) & 1u);       // round-to-nearest-even
    return (u16)(u >> 16);
}
__device__ __forceinline__ float b2f(u16 v) {
    return __uint_as_float(((uint32_t)v) << 16);
}
__device__ __forceinline__ float sigmoid_f(float v) { return 1.f / (1.f + __expf(-v)); }
__device__ __forceinline__ float gelu_f(float v) {
    return 0.5f * v * (1.f + erff(v * 0.70710678118654752f));
}

__device__ __forceinline__ void glds16(const u16* g, u16* l) {
    __builtin_amdgcn_global_load_lds(
        (const __attribute__((address_space(1))) void*)g,
        (__attribute__((address_space(3))) void*)l, 16, 0, 0);
}

// XCD-contiguous swizzle: XCD x = l&7 owns m-tiles [8x, 8x+8) for all n-tiles.
__device__ __forceinline__ void swiz8(int l, int& mt, int& nt) {
    mt = (l & 7) * 8 + ((l >> 3) & 7);
    nt = l >> 6;
}

// accL holds wave-rows 0..63 (i=0..3), accH rows 64..127 (i=4..7).
// ACC(i,j) with compile-time i folds the ternary (rule #20: no runtime index).
#define ACC(i, j) ((i) < 4 ? accL[(i) & 3][(j)] : accH[(i) & 3][(j)])

// ---------------------------------------------------------------------------
// NT GEMM, 2-phase-per-K-tile schedule (T3+T4+T5):
// out[m,n] = sum_k A[m,k]*W[n,k]; BM=256, BN=256, BK=32, 512 threads
// (8 waves 2x4, per-wave 128x64). 4-deep LDS K-tile ring (128KB), prefetch
// distance 3 K-tiles. Per K-tile:
//   P1: ds_read av[0..3]+bv[0..3] | stage A(kt+3) | barrier | 16 MFMA | barrier
//   P2: ds_read av[4..7]          | stage B(kt+3) | vmcnt(8)+barrier | 16 MFMA | barrier
// vmcnt(8) = 12 outstanding - 4 of next tile; counted, never 0 mid-loop.
// MODE 0: bf16 out (N=1024), bias
// MODE 1: bf16 out (N=2048), sigmoid, interleaved bias (even col->bias, odd->biasB)
// MODE 2: f32 out (N=1024) = v + bias + auxf[idx]
// MODE 3: N=2048 interleaved pair -> bf16 out (N=1024):
//         out[j] = gelu(sigmoid(v[2j]+bias[j])) * (v[2j+1]+biasB[j])
// ---------------------------------------------------------------------------
template <int MODE>
__global__ __launch_bounds__(512, 2)
void gemm256(const u16* __restrict__ A, const u16* __restrict__ Bw,
             const float* __restrict__ bias, const float* __restrict__ biasB,
             const float* __restrict__ auxf,
             u16* __restrict__ outb, float* __restrict__ outf)
{
    __shared__ __align__(16) u16 smem[65536];   // ring: 4 x (A 8192 + B 8192) u16

    int mt, nt; swiz8(blockIdx.x, mt, nt);
    const int m0 = mt * 256, n0 = nt * 256;
    const int tid = threadIdx.x;
    const int wave = tid >> 6, lane = tid & 63;
    const int wm = (wave >> 2) * 128, wn = (wave & 3) * 64;
    const int lr = lane & 15, lq = lane >> 4;

    // staging: thread stages LDS slot (trow, tcol); global k-chunk = tcol ^ ((trow>>1)&3)
    const int trow = tid >> 2, tcol = tid & 3;
    const int kswz = (tcol ^ ((trow >> 1) & 3)) * 8;
    const u16* Ag = A + (size_t)(m0 + trow) * DD + kswz;
    const u16* Bg = Bw + (size_t)(n0 + trow) * DD + kswz;
    const int st = tid * 8;
    const int cs = (lq ^ ((lr >> 1) & 3)) * 8;

    f32x4 accL[4][4] = {}, accH[4][4] = {};
    bf16x8 av[4], bv[4];

    auto SA = [&](int kt) {                     // stage A panel of tile kt (2 glds)
        u16* Ls = smem + (kt & 3) * 16384;
        const u16* a = Ag + (size_t)kt * 32;
        glds16(a, Ls + st);
        glds16(a + (size_t)128 * DD, Ls + 4096 + st);
    };
    auto SB = [&](int kt) {                     // stage B panel of tile kt (2 glds)
        u16* Ls = smem + (kt & 3) * 16384 + 8192;
        const u16* b = Bg + (size_t)kt * 32;
        glds16(b, Ls + st);
        glds16(b + (size_t)64 * DD + (size_t)64 * DD, Ls + 4096 + st);
    };
    auto RDA = [&](int kt, int rb) {            // rb = wm or wm+64
        const u16* Ls = smem + (kt & 3) * 16384;
#pragma unroll
        for (int i = 0; i < 4; i++)
            av[i] = *(const bf16x8*)&Ls[(rb + i * 16 + lr) * 32 + cs];
    };
    auto RDB = [&](int kt) {
        const u16* Ls = smem + (kt & 3) * 16384 + 8192;
#pragma unroll
        for (int j = 0; j < 4; j++)
            bv[j] = *(const bf16x8*)&Ls[(wn + j * 16 + lr) * 32 + cs];
    };
    auto MM16 = [&](f32x4 (&ac)[4][4]) {
        __builtin_amdgcn_s_setprio(1);
#pragma unroll
        for (int i = 0; i < 4; i++)
#pragma unroll
            for (int j = 0; j < 4; j++)
                ac[i][j] = __builtin_amdgcn_mfma_f32_16x16x32_bf16(
                    av[i], bv[j], ac[i][j], 0, 0, 0);
        __builtin_amdgcn_s_setprio(0);
    };

    // prologue: 3 K-tiles in flight; drain to 8 => tile 0 (oldest 4 loads) landed
    SA(0); SB(0); SA(1); SB(1); SA(2); SB(2);
    asm volatile("s_waitcnt vmcnt(8)\ns_barrier" ::: "memory");

#pragma unroll 4
    for (int kt = 0; kt < 29; ++kt) {
        // P1
        RDA(kt, wm); RDB(kt);
        SA(kt + 3);
        asm volatile("s_barrier" ::: "memory");
        MM16(accL);
        asm volatile("s_barrier" ::: "memory");
        // P2
        RDA(kt, wm + 64);
        SB(kt + 3);
        asm volatile("s_waitcnt vmcnt(8)\ns_barrier" ::: "memory");  // tile kt+1 landed
        MM16(accH);
        asm volatile("s_barrier" ::: "memory");
    }
    // kt = 29 (tiles 30,31 in flight)
    RDA(29, wm); RDB(29);
    asm volatile("s_barrier" ::: "memory");
    MM16(accL);
    asm volatile("s_barrier" ::: "memory");
    RDA(29, wm + 64);
    asm volatile("s_waitcnt vmcnt(4)\ns_barrier" ::: "memory");      // tile 30 landed
    MM16(accH);
    asm volatile("s_barrier" ::: "memory");
    // kt = 30
    RDA(30, wm); RDB(30);
    asm volatile("s_barrier" ::: "memory");
    MM16(accL);
    asm volatile("s_barrier" ::: "memory");
    RDA(30, wm + 64);
    asm volatile("s_waitcnt vmcnt(0)\ns_barrier" ::: "memory");      // tile 31 landed
    MM16(accH);
    asm volatile("s_barrier" ::: "memory");
    // kt = 31
    RDA(31, wm); RDB(31);
    MM16(accL);
    RDA(31, wm + 64);
    MM16(accH);

    // ---------------- epilogues (C/D layout: col=lane&15, row=(lane>>4)*4+reg) ----
    if constexpr (MODE == 0 || MODE == 1) {
        const int NW = (MODE == 1) ? 2048 : 1024;
        u16* ep = smem;
#pragma unroll                               // h compile-time: ACC index (rule #20)
        for (int h = 0; h < 4; ++h) {
            __syncthreads();
            if (wm == (h >> 1) * 128) {
                const int i0 = (h & 1) * 4;
#pragma unroll
                for (int ii = 0; ii < 4; ++ii) {
#pragma unroll
                    for (int j = 0; j < 4; ++j) {
                        const int col = wn + j * 16 + lr;
                        const int gc = n0 + col;
                        float bz;
                        if constexpr (MODE == 1)
                            bz = (gc & 1) ? biasB[gc >> 1] : bias[gc >> 1];
                        else
                            bz = bias[gc];
#pragma unroll
                        for (int p = 0; p < 4; ++p) {
                            float v = ACC(i0 + ii, j)[p] + bz;
                            if constexpr (MODE == 1) v = sigmoid_f(v);
                            ep[(ii * 16 + lq * 4 + p) * EPAD2 + col] = f2b(v);
                        }
                    }
                }
            }
            __syncthreads();
#pragma unroll
            for (int t = 0; t < 4; ++t) {
                const int f = t * 512 + tid;
                const int row = f >> 5, c8 = (f & 31) * 8;
                *(uint4*)&outb[(size_t)(m0 + h * 64 + row) * NW + n0 + c8] =
                    *(const uint4*)&ep[row * EPAD2 + c8];
            }
        }
    } else if constexpr (MODE == 2) {
#pragma unroll
        for (int i = 0; i < 8; ++i) {
            const int mrow = m0 + wm + (i & 3) * 16 + (i >> 2) * 64 + lq * 4;
#pragma unroll
            for (int j = 0; j < 4; ++j) {
                const int ncol = n0 + wn + j * 16 + lr;
                const float bz = bias[ncol];
#pragma unroll
                for (int p = 0; p < 4; ++p) {
                    const size_t idx = (size_t)(mrow + p) * DD + ncol;
                    outf[idx] = ((i < 4) ? accL[i & 3][j][p] : accH[i & 3][j][p])
                                + bz + auxf[idx];
                }
            }
        }
    } else {   // MODE 3: interleaved MLP combine, f32 LDS stage
        float* epf = (float*)smem;               // [64][EPADF]
#pragma unroll                               // h compile-time: ACC index (rule #20)
        for (int h = 0; h < 4; ++h) {
            __syncthreads();
            if (wm == (h >> 1) * 128) {
                const int i0 = (h & 1) * 4;
#pragma unroll
                for (int ii = 0; ii < 4; ++ii) {
#pragma unroll
                    for (int j = 0; j < 4; ++j) {
                        const int col = wn + j * 16 + lr;
                        const int gc = n0 + col;
                        const float bz = (gc & 1) ? biasB[gc >> 1] : bias[gc >> 1];
#pragma unroll
                        for (int p = 0; p < 4; ++p)
                            epf[(ii * 16 + lq * 4 + p) * EPADF + col] =
                                ACC(i0 + ii, j)[p] + bz;
                    }
                }
            }
            __syncthreads();
#pragma unroll
            for (int t = 0; t < 4; ++t) {
                const int f = t * 512 + tid;
                const int row = f >> 5, cg = (f & 31) * 4;   // 4 output cols
                const float4 v0 = *(const float4*)&epf[row * EPADF + cg * 2];
                const float4 v1 = *(const float4*)&epf[row * EPADF + cg * 2 + 4];
                ushort4 o4;
                o4.x = f2b(gelu_f(sigmoid_f(v0.x)) * v0.y);
                o4.y = f2b(gelu_f(sigmoid_f(v0.z)) * v0.w);
                o4.z = f2b(gelu_f(sigmoid_f(v1.x)) * v1.y);
                o4.w = f2b(gelu_f(sigmoid_f(v1.z)) * v1.w);
                *(ushort4*)&outb[(size_t)(m0 + h * 64 + row) * DD + (n0 >> 1) + cg] = o4;
            }
        }
    }
}

// ---------------------------------------------------------------------------
// RMSNorm: one block per row; out bf16 = x/max(||x||,1e-12)*sqrt(D)*g
// ---------------------------------------------------------------------------
__global__ __launch_bounds__(256)
void rmsnorm_k(const float* __restrict__ x, const float* __restrict__ g,
               u16* __restrict__ out)
{
    const int row = blockIdx.x;
    const int t = threadIdx.x;
    const float4 v = ((const float4*)(x + (size_t)row * DD))[t];
    float ss = v.x * v.x + v.y * v.y + v.z * v.z + v.w * v.w;
#pragma unroll
    for (int o = 32; o > 0; o >>= 1) ss += __shfl_down(ss, o, 64);
    __shared__ float wsum[4];
    if ((t & 63) == 0) wsum[t >> 6] = ss;
    __syncthreads();
    const float tot = wsum[0] + wsum[1] + wsum[2] + wsum[3];
    const float sc = 32.0f * rsqrtf(fmaxf(tot, 1e-24f));
    const float4 gv = ((const float4*)g)[t];
    ushort4 o4;
    o4.x = f2b(v.x * sc * gv.x);
    o4.y = f2b(v.y * sc * gv.y);
    o4.z = f2b(v.z * sc * gv.z);
    o4.w = f2b(v.w * sc * gv.w);
    ((ushort4*)(out + (size_t)row * DD))[t] = o4;
}

// ---------------------------------------------------------------------------
// fp32 -> bf16 weight conversion.
// conv_plain: 4 plain matrices. conv_inter: 2 row-interleaved pairs
// (dst row 2j = srcA row j, dst row 2j+1 = srcB row j).
// ---------------------------------------------------------------------------
struct WP { const float* s[4]; unsigned off[4]; };
__global__ __launch_bounds__(256)
void conv_plain(WP w, u16* __restrict__ out)
{
    const float* in = w.s[blockIdx.y];
    u16* o = out + (size_t)w.off[blockIdx.y];
    const int i = (blockIdx.x * 256 + threadIdx.x) * 4;
    const float4 v = *(const float4*)(in + i);
    ushort4 r;
    r.x = f2b(v.x); r.y = f2b(v.y); r.z = f2b(v.z); r.w = f2b(v.w);
    *(ushort4*)(o + i) = r;
}
struct WI { const float* a[2]; const float* b[2]; unsigned off[2]; };
__global__ __launch_bounds__(256)
void conv_inter(WI w, u16* __restrict__ out)
{
    u16* o = out + (size_t)w.off[blockIdx.y];
    const int e = (blockIdx.x * 256 + threadIdx.x) * 4;   // < 2M
    const int row = e >> 10, col = e & 1023;
    const float* src = (row & 1) ? w.b[blockIdx.y] : w.a[blockIdx.y];
    const float4 v = *(const float4*)(src + ((size_t)(row >> 1) << 10) + col);
    ushort4 r;
    r.x = f2b(v.x); r.y = f2b(v.y); r.z = f2b(v.z); r.w = f2b(v.w);
    *(ushort4*)(o + e) = r;
}

// ---------------------------------------------------------------------------
// RG-LRU chunked scan, interleaved rt/it input (col 2d = rt, 2d+1 = it).
// h[t] = a[t]*h[t-1] + g[t]; a = exp(log_a * rt / 8); g = sqrt(1-a^2)*it*x
// ---------------------------------------------------------------------------
__global__ __launch_bounds__(256)
void scan_chunks(const u16* __restrict__ rtit, const u16* __restrict__ rg,
                 const float* __restrict__ Lam,
                 float* __restrict__ P, float* __restrict__ Hl)
{
    const int d = blockIdx.x * 256 + threadIdx.x;
    const int c = blockIdx.y, b = blockIdx.z;
    const float k = -log1pf(__expf(-Lam[d])) * 0.125f;
    const size_t base1 = (((size_t)b * 4096) + (size_t)c * CLEN) * DD + d;
    const size_t base2 = (((size_t)b * 4096) + (size_t)c * CLEN) * 2048 + 2 * d;
    float p = 1.f, h = 0.f;
#pragma unroll 4
    for (int t = 0; t < CLEN; t++) {
        const uint32_t w = *(const uint32_t*)&rtit[base2 + (size_t)t * 2048];
        const float r = b2f((u16)(w & 0xffffu));
        const float i = b2f((u16)(w >> 16));
        const float xv = b2f(rg[base1 + (size_t)t * DD]);
        const float a = __expf(k * r);
        const float g = sqrtf(fmaxf(1.f - a * a, 0.f)) * (i * xv);
        p *= a;
        h = fmaf(a, h, g);
    }
    const int o = (b * NCH + c) * DD + d;
    P[o] = p;
    Hl[o] = h;
}

__global__ __launch_bounds__(256)
void scan_carry(const float* __restrict__ P, const float* __restrict__ Hl,
                float* __restrict__ Cin)
{
    const int idx = blockIdx.x * 256 + threadIdx.x;  // B*D = 4096
    const int b = idx >> 10, d = idx & 1023;
    float h = 0.f;
    for (int c = 0; c < NCH; c++) {
        const int o = (b * NCH + c) * DD + d;
        Cin[o] = h;
        h = fmaf(P[o], h, Hl[o]);
    }
}

__global__ __launch_bounds__(256)
void scan_apply(const u16* __restrict__ rtit, const u16* __restrict__ rg,
                const u16* __restrict__ lin, const float* __restrict__ Lam,
                const float* __restrict__ Cin, u16* __restrict__ yin)
{
    const int d = blockIdx.x * 256 + threadIdx.x;
    const int c = blockIdx.y, b = blockIdx.z;
    const float k = -log1pf(__expf(-Lam[d])) * 0.125f;
    const size_t base1 = (((size_t)b * 4096) + (size_t)c * CLEN) * DD + d;
    const size_t base2 = (((size_t)b * 4096) + (size_t)c * CLEN) * 2048 + 2 * d;
    float h = Cin[(b * NCH + c) * DD + d];
#pragma unroll 4
    for (int t = 0; t < CLEN; t++) {
        const uint32_t w = *(const uint32_t*)&rtit[base2 + (size_t)t * 2048];
        const float r = b2f((u16)(w & 0xffffu));
        const float i = b2f((u16)(w >> 16));
        const size_t ix = base1 + (size_t)t * DD;
        const float xv = b2f(rg[ix]);
        const float a = __expf(k * r);
        const float g = sqrtf(fmaxf(1.f - a * a, 0.f)) * (i * xv);
        h = fmaf(a, h, g);
        const float l = b2f(lin[ix]);
        yin[ix] = f2b(gelu_f(l) * h);
    }
}

// ---------------------------------------------------------------------------
extern "C" void kernel_launch(void* const* d_in, const int* in_sizes, int n_in,
                              void* d_out, int out_size, void* d_ws, size_t ws_size,
                              hipStream_t stream)
{
    const float* x      = (const float*)d_in[0];
    const float* g1     = (const float*)d_in[1];
    const float* g2     = (const float*)d_in[2];
    const float* W_lin  = (const float*)d_in[3];
    const float* b_lin  = (const float*)d_in[4];
    const float* W_conv = (const float*)d_in[5];
    const float* b_conv = (const float*)d_in[6];
    const float* W_lin2 = (const float*)d_in[7];
    const float* b_lin2 = (const float*)d_in[8];
    const float* Wa     = (const float*)d_in[9];
    const float* ba     = (const float*)d_in[10];
    const float* Wx     = (const float*)d_in[11];
    const float* bx     = (const float*)d_in[12];
    const float* Lam    = (const float*)d_in[13];
    const float* W1     = (const float*)d_in[14];
    const float* b1     = (const float*)d_in[15];
    const float* W2     = (const float*)d_in[16];
    const float* b2     = (const float*)d_in[17];
    const float* W3     = (const float*)d_in[18];
    const float* b3     = (const float*)d_in[19];
    float* out = (float*)d_out;

    char* p = (char*)d_ws;
    auto alloc = [&](size_t bytes) -> char* {
        char* q = p;
        p += (bytes + 255) & ~(size_t)255;
        return q;
    };
    const size_t MD = (size_t)MM * DD;
    const size_t M1 = (size_t)DD * DD;        // 1M elements
    u16* wball = (u16*)alloc((size_t)8 * M1 * 2);   // 16MB
    u16* t1   = (u16*)alloc(MD * 2);                // lin
    u16* t2   = (u16*)alloc(MD * 2);                // rg, later combined
    u16* t4   = (u16*)alloc(MD * 2);                // xn -> yin -> xm
    u16* rtit = (u16*)alloc(MD * 4);                // interleaved rt/it (16384x2048)
    float* res2 = (float*)alloc(MD * 4);
    float* P   = (float*)alloc((size_t)4 * NCH * DD * 4);
    float* Hl  = (float*)alloc((size_t)4 * NCH * DD * 4);
    float* Cin = (float*)alloc((size_t)4 * NCH * DD * 4);

    // wball layout (u16 elem offsets):
    //  [0]   W_lin   [1M] W_conv   [2M] WaWx(2M, interleaved)
    //  [4M]  W_lin2  [5M] W1W2(2M, interleaved)  [7M] W3
    WP wp;
    wp.s[0] = W_lin;  wp.off[0] = 0;
    wp.s[1] = W_conv; wp.off[1] = 1u << 20;
    wp.s[2] = W_lin2; wp.off[2] = 4u << 20;
    wp.s[3] = W3;     wp.off[3] = 7u << 20;
    conv_plain<<<dim3(M1 / 1024, 4), 256, 0, stream>>>(wp, wball);
    WI wi;
    wi.a[0] = Wa; wi.b[0] = Wx; wi.off[0] = 2u << 20;
    wi.a[1] = W1; wi.b[1] = W2; wi.off[1] = 5u << 20;
    conv_inter<<<dim3(2 * M1 / 1024, 2), 256, 0, stream>>>(wi, wball);

    const u16* wLin  = wball;
    const u16* wConv = wball + (1u << 20);
    const u16* wAX   = wball + (2u << 20);
    const u16* wLin2 = wball + (4u << 20);
    const u16* w12   = wball + (5u << 20);
    const u16* w3    = wball + (7u << 20);

    const int gs = (MM / 256) * (DD / 256);        // 256 blocks (N=1024)
    const int gw = (MM / 256) * (2 * DD / 256);    // 512 blocks (N=2048)
    const dim3 sg(DD / 256, NCH, 4);

    // xn = rmsnorm(x)*g1
    rmsnorm_k<<<MM, 256, 0, stream>>>(x, g1, t4);
    // lin = xn@W_lin.T + b_lin
    gemm256<0><<<gs, 512, 0, stream>>>(t4, wLin, b_lin, nullptr, nullptr, t1, nullptr);
    // rg = lin@W_conv.T + b_conv
    gemm256<0><<<gs, 512, 0, stream>>>(t1, wConv, b_conv, nullptr, nullptr, t2, nullptr);
    // rtit = sigmoid(rg@[Wa||Wx interleaved].T + [ba||bx])
    gemm256<1><<<gw, 512, 0, stream>>>(t2, wAX, ba, bx, nullptr, rtit, nullptr);
    // RG-LRU scan + yin = gelu(lin)*h
    scan_chunks<<<sg, 256, 0, stream>>>(rtit, t2, Lam, P, Hl);
    scan_carry<<<4096 / 256, 256, 0, stream>>>(P, Hl, Cin);
    scan_apply<<<sg, 256, 0, stream>>>(rtit, t2, t1, Lam, Cin, t4);
    // res2 = yin@W_lin2.T + b_lin2 + x
    gemm256<2><<<gs, 512, 0, stream>>>(t4, wLin2, b_lin2, nullptr, x, nullptr, res2);
    // xm = rmsnorm(res2)*g2
    rmsnorm_k<<<MM, 256, 0, stream>>>(res2, g2, t4);
    // combined = gelu(sigmoid(xm@W1.T+b1)) * (xm@W2.T+b2)   (interleaved pair GEMM)
    gemm256<3><<<gw, 512, 0, stream>>>(t4, w12, b1, b2, nullptr, t2, nullptr);
    // y = combined@W3.T + b3 + res2
    gemm256<2><<<gs, 512, 0, stream>>>(t2, w3, b3, nullptr, res2, nullptr, out);
}